// Round 6
// baseline (473.802 us; speedup 1.0000x reference)
//
#include <hip/hip_runtime.h>

#define N_OSC 50
#define N_PER 40
#define DT 0.01f
#define STEPS 100
#define BATCH 8192

typedef float v2f __attribute__((ext_vector_type(2)));

static __device__ __forceinline__ v2f fma2(v2f a, v2f b, v2f c) {
    return __builtin_elementwise_fma(a, b, c);
}

// ws layout (float offsets)
#define WS_PC     0        // 50*240 = 12000 packed consts
#define WS_DIRECT 12288    // 8192
#define WS_O0     20480    // 100*8192
#define WS_TORQ   839680   // 100*8192 torque accumulator

// ---------------------------------------------------------------------------
// Fused prep + MLP. Blocks [0,800): zero torq (float4 each thread); blocks
// [0,8) additionally pack per-osc constants. Blocks [800,1056): the MLP.
// Packed consts per osc (stride 240 floats):
//   [0..79]    E: chunk c -> (e0 of unit 2c, e0 of 2c+1, e1 of 2c, e1 of 2c+1)
//   [80..159]  D: chunk c -> (d0 of 2c, d0 of 2c+1, d1 of 2c, d1 of 2c+1)
//   [160..199] W: chunk c -> (w4 of 2c, w4 of 2c+1)
//   [200..239] OB: obias[n] natural order
// ---------------------------------------------------------------------------
__global__ __launch_bounds__(256) void prep_mlp_kernel(
    const float* __restrict__ x,
    const float* __restrict__ fc1_w, const float* __restrict__ fc1_b,
    const float* __restrict__ fc2_w, const float* __restrict__ fc2_b,
    const float* __restrict__ fc3_w, const float* __restrict__ fc3_b,
    const float* __restrict__ fcd_w, const float* __restrict__ fcd_b,
    const float* __restrict__ enc, const float* __restrict__ obias,
    const float* __restrict__ dec, const float* __restrict__ fc4_w,
    float* __restrict__ pc, float* __restrict__ torq,
    float* __restrict__ o0out, float* __restrict__ directout) {
    __shared__ float hs[32 * 132];
    __shared__ float h2s[32 * 132];
    int blk = blockIdx.x;
    int tid = threadIdx.x;

    if (blk < 800) {
        int idx = blk * 256 + tid;
        ((float4*)torq)[idx] = make_float4(0.f, 0.f, 0.f, 0.f);  // 819200 floats
        if (idx < N_OSC * N_PER) {
            int o = idx / N_PER, n = idx - o * N_PER;
            int c = n >> 1, h = n & 1;
            float* base = pc + o * 240;
            base[4 * c + h]           = enc[o * 80 + 2 * n + 0];
            base[4 * c + 2 + h]       = enc[o * 80 + 2 * n + 1];
            base[80 + 4 * c + h]      = dec[o * 80 + n];         // dec[o][0][n]
            base[80 + 4 * c + 2 + h]  = dec[o * 80 + 40 + n];    // dec[o][1][n]
            base[160 + 2 * c + h]     = fc4_w[o * 40 + n];
            base[200 + n]             = obias[o * 40 + n];
        }
        return;
    }

    int bb = tid & 31;
    int hw = tid >> 5;             // 0..7
    int b0 = (blk - 800) * 32;

    // fc1: h = relu(x @ fc1_w.T + b1), 32x128 outputs
    for (int idx = tid; idx < 32 * 128; idx += 256) {
        int r = idx >> 7, j = idx & 127;
        float x0 = x[(b0 + r) * 2], x1 = x[(b0 + r) * 2 + 1];
        float v = fmaf(x0, fc1_w[j * 2], fmaf(x1, fc1_w[j * 2 + 1], fc1_b[j]));
        hs[r * 132 + j] = fmaxf(v, 0.f);
    }
    __syncthreads();

    // direct = h . fcd_w + fcd_b
    if (tid < 32) {
        float s = fcd_b[0];
        #pragma unroll 8
        for (int k = 0; k < 128; k += 4) {
            float4 h4 = *(const float4*)&hs[tid * 132 + k];
            float4 w4 = *(const float4*)&fcd_w[k];
            s = fmaf(h4.x, w4.x, fmaf(h4.y, w4.y, fmaf(h4.z, w4.z, fmaf(h4.w, w4.w, s))));
        }
        directout[b0 + tid] = s;
    }

    // fc2: h2 = relu(h @ fc2_w.T + b2)
    for (int pass = 0; pass < 4; ++pass) {
        int j0 = hw * 16 + pass * 4;
        float a0 = fc2_b[j0], a1 = fc2_b[j0 + 1], a2 = fc2_b[j0 + 2], a3 = fc2_b[j0 + 3];
        const float* w0 = fc2_w + j0 * 128;
        const float* w1 = w0 + 128;
        const float* w2 = w0 + 256;
        const float* w3 = w0 + 384;
        #pragma unroll 8
        for (int k = 0; k < 128; k += 4) {
            float4 h4 = *(const float4*)&hs[bb * 132 + k];
            float4 q0 = *(const float4*)&w0[k];
            float4 q1 = *(const float4*)&w1[k];
            float4 q2 = *(const float4*)&w2[k];
            float4 q3 = *(const float4*)&w3[k];
            a0 = fmaf(h4.x, q0.x, fmaf(h4.y, q0.y, fmaf(h4.z, q0.z, fmaf(h4.w, q0.w, a0))));
            a1 = fmaf(h4.x, q1.x, fmaf(h4.y, q1.y, fmaf(h4.z, q1.z, fmaf(h4.w, q1.w, a1))));
            a2 = fmaf(h4.x, q2.x, fmaf(h4.y, q2.y, fmaf(h4.z, q2.z, fmaf(h4.w, q2.w, a2))));
            a3 = fmaf(h4.x, q3.x, fmaf(h4.y, q3.y, fmaf(h4.z, q3.z, fmaf(h4.w, q3.w, a3))));
        }
        h2s[bb * 132 + j0]     = fmaxf(a0, 0.f);
        h2s[bb * 132 + j0 + 1] = fmaxf(a1, 0.f);
        h2s[bb * 132 + j0 + 2] = fmaxf(a2, 0.f);
        h2s[bb * 132 + j0 + 3] = fmaxf(a3, 0.f);
    }
    __syncthreads();

    // fc3: x3 (100 outputs) -> o0out[j][b]
    for (int pass = 0; pass < 4; ++pass) {
        int j0 = pass * 32 + hw * 4;
        if (j0 >= 100) continue;
        float a0 = fc3_b[j0], a1 = fc3_b[j0 + 1], a2 = fc3_b[j0 + 2], a3 = fc3_b[j0 + 3];
        const float* w0 = fc3_w + j0 * 128;
        const float* w1 = w0 + 128;
        const float* w2 = w0 + 256;
        const float* w3 = w0 + 384;
        #pragma unroll 8
        for (int k = 0; k < 128; k += 4) {
            float4 h4 = *(const float4*)&h2s[bb * 132 + k];
            float4 q0 = *(const float4*)&w0[k];
            float4 q1 = *(const float4*)&w1[k];
            float4 q2 = *(const float4*)&w2[k];
            float4 q3 = *(const float4*)&w3[k];
            a0 = fmaf(h4.x, q0.x, fmaf(h4.y, q0.y, fmaf(h4.z, q0.z, fmaf(h4.w, q0.w, a0))));
            a1 = fmaf(h4.x, q1.x, fmaf(h4.y, q1.y, fmaf(h4.z, q1.z, fmaf(h4.w, q1.w, a1))));
            a2 = fmaf(h4.x, q2.x, fmaf(h4.y, q2.y, fmaf(h4.z, q2.z, fmaf(h4.w, q2.w, a2))));
            a3 = fmaf(h4.x, q3.x, fmaf(h4.y, q3.y, fmaf(h4.z, q3.z, fmaf(h4.w, q3.w, a3))));
        }
        o0out[(j0)     * BATCH + b0 + bb] = a0;
        o0out[(j0 + 1) * BATCH + b0 + bb] = a1;
        o0out[(j0 + 2) * BATCH + b0 + bb] = a2;
        o0out[(j0 + 3) * BATCH + b0 + bb] = a3;
    }
}

// ---------------------------------------------------------------------------
// Phase A: one oscillator per BLOCK (256 thr = 4 waves), 10 units per wave.
// Per-wave constants = 30 v2f = 60 VGPRs -> register-resident without
// fighting the allocator. Per-step cross-wave coupling: each wave writes
// {d0,d1,tq} float4 to LDS, one barrier, all waves read all 4 slots in fixed
// order (identical FP order -> identical state in all waves). Wave 0 fires
// one torque atomic per block per step. Step-parity double buffer -> one
// __syncthreads per step.
// ---------------------------------------------------------------------------
__global__ __launch_bounds__(256, 4) void osc_kernel(const float* __restrict__ pc,
                                                     const float* __restrict__ o0init,
                                                     float* __restrict__ torq) {
    __shared__ float cs[240];
    __shared__ float4 xch[2][256];
    int blk = blockIdx.x;
    int bg = blk / N_OSC;          // 0..127
    int osc = blk - bg * N_OSC;    // 0..49
    int tid = threadIdx.x;
    int lane = tid & 63;
    int w = tid >> 6;              // 0..3
    int b = bg * 64 + lane;

    if (tid < 60)
        ((float4*)cs)[tid] = ((const float4*)(pc + osc * 240))[tid];
    __syncthreads();

    // This wave's 5 chunks (units 10w .. 10w+9) -> 30 v2f = 60 VGPRs.
    v2f e0[5], e1[5], d0c[5], d1c[5], wcv[5], obv[5];
    int c0 = w * 5;
    #pragma unroll
    for (int i = 0; i < 5; ++i) {
        int c = c0 + i;
        e0[i]  = *(const v2f*)(cs + 4 * c);
        e1[i]  = *(const v2f*)(cs + 4 * c + 2);
        d0c[i] = *(const v2f*)(cs + 80 + 4 * c);
        d1c[i] = *(const v2f*)(cs + 80 + 4 * c + 2);
        wcv[i] = *(const v2f*)(cs + 160 + 2 * c);
        obv[i] = *(const v2f*)(cs + 200 + 2 * c);
    }

    float s0 = o0init[(2 * osc) * BATCH + b];
    float s1 = o0init[(2 * osc + 1) * BATCH + b];

    for (int step = 0; step < STEPS; ++step) {
        v2f o0p = (v2f){s0, s0};
        v2f o1p = (v2f){s1, s1};
        v2f tq = (v2f){0.f, 0.f};
        v2f D0 = (v2f){0.f, 0.f};
        v2f D1 = (v2f){0.f, 0.f};
        #pragma unroll
        for (int i = 0; i < 5; ++i) {
            v2f a = fma2(o0p, e0[i], fma2(o1p, e1[i], obv[i]));
            a = __builtin_elementwise_max(a, (v2f){0.f, 0.f});
            tq = fma2(a, wcv[i], tq);
            D0 = fma2(a, d0c[i], D0);
            D1 = fma2(a, d1c[i], D1);
        }
        int p = step & 1;
        xch[p][tid] = make_float4(D0.x + D0.y, D1.x + D1.y, tq.x + tq.y, 0.f);
        __syncthreads();
        float4 q0 = xch[p][lane];
        float4 q1 = xch[p][64 + lane];
        float4 q2 = xch[p][128 + lane];
        float4 q3 = xch[p][192 + lane];
        float dd0 = (q0.x + q1.x) + (q2.x + q3.x);
        float dd1 = (q0.y + q1.y) + (q2.y + q3.y);
        s0 = fmaf(DT, dd0, s0);
        s1 = fmaf(DT, dd1, s1);
        if (w == 0) {
            float tt = (q0.z + q1.z) + (q2.z + q3.z);
            atomicAdd(&torq[step * BATCH + b], tt);
        }
    }
}

// ---------------------------------------------------------------------------
// Phase B: integrate pendulum; prefetch torq; packed float2 state store.
// ---------------------------------------------------------------------------
__global__ __launch_bounds__(64) void pend_kernel(const float* __restrict__ x,
                                                  const float* __restrict__ torq,
                                                  const float* __restrict__ direct,
                                                  const float* __restrict__ fc4_b,
                                                  float* __restrict__ out) {
    int b = blockIdx.x * 64 + threadIdx.x;
    float theta = x[2 * b];
    float omega = 0.f;
    float base = direct[b] + fc4_b[0];
    float2* out_l = (float2*)out;             // (100, 8192, 2)
    float* out_t = out + STEPS * BATCH * 2;   // (100, 8192)
    float pf[4];
    #pragma unroll
    for (int j = 0; j < 4; ++j) pf[j] = torq[j * BATCH + b];
    #pragma unroll 4
    for (int s = 0; s < STEPS; ++s) {
        float tq = base + pf[s & 3];
        if (s + 4 < STEPS) pf[s & 3] = torq[(s + 4) * BATCH + b];
        float alpha = tq - __sinf(theta) - 0.1f * omega;   // old theta, old omega
        theta = fmaf(DT, omega, theta);                    // uses old omega
        omega = fmaf(DT, alpha, omega);
        out_l[s * BATCH + b] = make_float2(theta, omega);
        out_t[s * BATCH + b] = tq;
    }
}

extern "C" void kernel_launch(void* const* d_in, const int* in_sizes, int n_in,
                              void* d_out, int out_size, void* d_ws, size_t ws_size,
                              hipStream_t stream) {
    const float* x     = (const float*)d_in[0];
    const float* fc1_w = (const float*)d_in[1];
    const float* fc1_b = (const float*)d_in[2];
    const float* fc2_w = (const float*)d_in[3];
    const float* fc2_b = (const float*)d_in[4];
    const float* fc3_w = (const float*)d_in[5];
    const float* fc3_b = (const float*)d_in[6];
    const float* fcd_w = (const float*)d_in[7];
    const float* fcd_b = (const float*)d_in[8];
    const float* enc   = (const float*)d_in[9];
    const float* obias = (const float*)d_in[10];
    const float* dec   = (const float*)d_in[11];
    const float* fc4_w = (const float*)d_in[12];
    const float* fc4_b = (const float*)d_in[13];
    float* out = (float*)d_out;
    float* ws = (float*)d_ws;

    float* pc      = ws + WS_PC;
    float* direct  = ws + WS_DIRECT;
    float* o0      = ws + WS_O0;
    float* torq    = ws + WS_TORQ;

    hipLaunchKernelGGL(prep_mlp_kernel, dim3(800 + 256), dim3(256), 0, stream,
                       x, fc1_w, fc1_b, fc2_w, fc2_b, fc3_w, fc3_b,
                       fcd_w, fcd_b, enc, obias, dec, fc4_w,
                       pc, torq, o0, direct);
    hipLaunchKernelGGL(osc_kernel, dim3(128 * N_OSC), dim3(256), 0, stream,
                       pc, o0, torq);
    hipLaunchKernelGGL(pend_kernel, dim3(BATCH / 64), dim3(64), 0, stream,
                       x, torq, direct, fc4_b, out);
}

// Round 7
// 449.575 us; speedup vs baseline: 1.0539x; 1.0539x over previous
//
#include <hip/hip_runtime.h>

#define N_OSC 50
#define N_PER 40
#define DT 0.01f
#define STEPS 100
#define BATCH 8192

typedef float v2f __attribute__((ext_vector_type(2)));

static __device__ __forceinline__ v2f fma2(v2f a, v2f b, v2f c) {
    return __builtin_elementwise_fma(a, b, c);
}

// ws layout (float offsets)
#define WS_PC     0        // 50*240 = 12000 packed consts
#define WS_DIRECT 12288    // 8192
#define WS_O0     20480    // 100*8192
#define WS_TORQ   839680   // 100*8192 torque accumulator

// ---------------------------------------------------------------------------
// Fused prep + MLP. Blocks [0,800): zero torq; blocks [0,8) pack consts.
// Blocks [800,1056): MLP.
// Packed consts per osc (stride 240 floats):
//   [0..79]    E: chunk c -> (e0 of unit 2c, e0 of 2c+1, e1 of 2c, e1 of 2c+1)
//   [80..159]  D: chunk c -> (d0 of 2c, d0 of 2c+1, d1 of 2c, d1 of 2c+1)
//   [160..199] W: chunk c -> (w4 of 2c, w4 of 2c+1)
//   [200..239] OB: chunk c -> (ob of 2c, ob of 2c+1)
// ---------------------------------------------------------------------------
__global__ __launch_bounds__(256) void prep_mlp_kernel(
    const float* __restrict__ x,
    const float* __restrict__ fc1_w, const float* __restrict__ fc1_b,
    const float* __restrict__ fc2_w, const float* __restrict__ fc2_b,
    const float* __restrict__ fc3_w, const float* __restrict__ fc3_b,
    const float* __restrict__ fcd_w, const float* __restrict__ fcd_b,
    const float* __restrict__ enc, const float* __restrict__ obias,
    const float* __restrict__ dec, const float* __restrict__ fc4_w,
    float* __restrict__ pc, float* __restrict__ torq,
    float* __restrict__ o0out, float* __restrict__ directout) {
    __shared__ float hs[32 * 132];
    __shared__ float h2s[32 * 132];
    int blk = blockIdx.x;
    int tid = threadIdx.x;

    if (blk < 800) {
        int idx = blk * 256 + tid;
        ((float4*)torq)[idx] = make_float4(0.f, 0.f, 0.f, 0.f);  // 819200 floats
        if (idx < N_OSC * N_PER) {
            int o = idx / N_PER, n = idx - o * N_PER;
            int c = n >> 1, h = n & 1;
            float* base = pc + o * 240;
            base[4 * c + h]           = enc[o * 80 + 2 * n + 0];
            base[4 * c + 2 + h]       = enc[o * 80 + 2 * n + 1];
            base[80 + 4 * c + h]      = dec[o * 80 + n];         // dec[o][0][n]
            base[80 + 4 * c + 2 + h]  = dec[o * 80 + 40 + n];    // dec[o][1][n]
            base[160 + 2 * c + h]     = fc4_w[o * 40 + n];
            base[200 + 2 * c + h]     = obias[o * 40 + n];
        }
        return;
    }

    int bb = tid & 31;
    int hw = tid >> 5;             // 0..7
    int b0 = (blk - 800) * 32;

    for (int idx = tid; idx < 32 * 128; idx += 256) {
        int r = idx >> 7, j = idx & 127;
        float x0 = x[(b0 + r) * 2], x1 = x[(b0 + r) * 2 + 1];
        float v = fmaf(x0, fc1_w[j * 2], fmaf(x1, fc1_w[j * 2 + 1], fc1_b[j]));
        hs[r * 132 + j] = fmaxf(v, 0.f);
    }
    __syncthreads();

    if (tid < 32) {
        float s = fcd_b[0];
        #pragma unroll 8
        for (int k = 0; k < 128; k += 4) {
            float4 h4 = *(const float4*)&hs[tid * 132 + k];
            float4 w4 = *(const float4*)&fcd_w[k];
            s = fmaf(h4.x, w4.x, fmaf(h4.y, w4.y, fmaf(h4.z, w4.z, fmaf(h4.w, w4.w, s))));
        }
        directout[b0 + tid] = s;
    }

    for (int pass = 0; pass < 4; ++pass) {
        int j0 = hw * 16 + pass * 4;
        float a0 = fc2_b[j0], a1 = fc2_b[j0 + 1], a2 = fc2_b[j0 + 2], a3 = fc2_b[j0 + 3];
        const float* w0 = fc2_w + j0 * 128;
        const float* w1 = w0 + 128;
        const float* w2 = w0 + 256;
        const float* w3 = w0 + 384;
        #pragma unroll 8
        for (int k = 0; k < 128; k += 4) {
            float4 h4 = *(const float4*)&hs[bb * 132 + k];
            float4 q0 = *(const float4*)&w0[k];
            float4 q1 = *(const float4*)&w1[k];
            float4 q2 = *(const float4*)&w2[k];
            float4 q3 = *(const float4*)&w3[k];
            a0 = fmaf(h4.x, q0.x, fmaf(h4.y, q0.y, fmaf(h4.z, q0.z, fmaf(h4.w, q0.w, a0))));
            a1 = fmaf(h4.x, q1.x, fmaf(h4.y, q1.y, fmaf(h4.z, q1.z, fmaf(h4.w, q1.w, a1))));
            a2 = fmaf(h4.x, q2.x, fmaf(h4.y, q2.y, fmaf(h4.z, q2.z, fmaf(h4.w, q2.w, a2))));
            a3 = fmaf(h4.x, q3.x, fmaf(h4.y, q3.y, fmaf(h4.z, q3.z, fmaf(h4.w, q3.w, a3))));
        }
        h2s[bb * 132 + j0]     = fmaxf(a0, 0.f);
        h2s[bb * 132 + j0 + 1] = fmaxf(a1, 0.f);
        h2s[bb * 132 + j0 + 2] = fmaxf(a2, 0.f);
        h2s[bb * 132 + j0 + 3] = fmaxf(a3, 0.f);
    }
    __syncthreads();

    for (int pass = 0; pass < 4; ++pass) {
        int j0 = pass * 32 + hw * 4;
        if (j0 >= 100) continue;
        float a0 = fc3_b[j0], a1 = fc3_b[j0 + 1], a2 = fc3_b[j0 + 2], a3 = fc3_b[j0 + 3];
        const float* w0 = fc3_w + j0 * 128;
        const float* w1 = w0 + 128;
        const float* w2 = w0 + 256;
        const float* w3 = w0 + 384;
        #pragma unroll 8
        for (int k = 0; k < 128; k += 4) {
            float4 h4 = *(const float4*)&h2s[bb * 132 + k];
            float4 q0 = *(const float4*)&w0[k];
            float4 q1 = *(const float4*)&w1[k];
            float4 q2 = *(const float4*)&w2[k];
            float4 q3 = *(const float4*)&w3[k];
            a0 = fmaf(h4.x, q0.x, fmaf(h4.y, q0.y, fmaf(h4.z, q0.z, fmaf(h4.w, q0.w, a0))));
            a1 = fmaf(h4.x, q1.x, fmaf(h4.y, q1.y, fmaf(h4.z, q1.z, fmaf(h4.w, q1.w, a1))));
            a2 = fmaf(h4.x, q2.x, fmaf(h4.y, q2.y, fmaf(h4.z, q2.z, fmaf(h4.w, q2.w, a2))));
            a3 = fmaf(h4.x, q3.x, fmaf(h4.y, q3.y, fmaf(h4.z, q3.z, fmaf(h4.w, q3.w, a3))));
        }
        o0out[(j0)     * BATCH + b0 + bb] = a0;
        o0out[(j0 + 1) * BATCH + b0 + bb] = a1;
        o0out[(j0 + 2) * BATCH + b0 + bb] = a2;
        o0out[(j0 + 3) * BATCH + b0 + bb] = a3;
    }
}

// ---------------------------------------------------------------------------
// Phase A: one oscillator per WAVE, units split across lane quads.
//   ug = lane&3  : unit-quarter (10 units = 5 packed chunks per lane)
//   bl = lane>>2 : 16 batch elements per wave
// Constants are PER-LANE GLOBAL loads (divergent by ug -> compiler keeps them
// in VGPRs; a reload would cost vmcnt). Per-step cross-ug reduction =
// 2-stage __shfl_xor(1,2) butterfly (quad_perm DPP, pure VALU). No LDS, no
// barriers in the hot loop. ug==0 lanes fire the torque atomic.
// ---------------------------------------------------------------------------
__global__ __launch_bounds__(256) void osc_kernel(const float* __restrict__ pc,
                                                  const float* __restrict__ o0init,
                                                  float* __restrict__ torq) {
    int tid = threadIdx.x;
    int w = __builtin_amdgcn_readfirstlane(tid >> 6);
    int lane = tid & 63;
    int W = blockIdx.x * 4 + w;        // 0..25599
    int bg = W / N_OSC;                // 0..511
    int osc = W - bg * N_OSC;          // 0..49
    int ug = lane & 3;
    int b = bg * 16 + (lane >> 2);

    const float* __restrict__ base = pc + osc * 240;

    float4 E[5], Dv[5];
    v2f Wv[5], OB[5];
    #pragma unroll
    for (int i = 0; i < 5; ++i) {
        int c = ug * 5 + i;
        E[i]  = *(const float4*)(base + 4 * c);        // e0(2c),e0(2c+1),e1(2c),e1(2c+1)
        Dv[i] = *(const float4*)(base + 80 + 4 * c);   // d0 pair, d1 pair
        Wv[i] = *(const v2f*)(base + 160 + 2 * c);
        OB[i] = *(const v2f*)(base + 200 + 2 * c);
    }
    // Pin in VGPRs (defensive; global-sourced values should stay anyway).
    #pragma unroll
    for (int i = 0; i < 5; ++i) {
        asm volatile("" : "+v"(E[i].x), "+v"(E[i].y), "+v"(E[i].z), "+v"(E[i].w));
        asm volatile("" : "+v"(Dv[i].x), "+v"(Dv[i].y), "+v"(Dv[i].z), "+v"(Dv[i].w));
        asm volatile("" : "+v"(Wv[i]), "+v"(OB[i]));
    }

    float s0 = o0init[(2 * osc) * BATCH + b];
    float s1 = o0init[(2 * osc + 1) * BATCH + b];
    float* tp = torq + b;

    for (int step = 0; step < STEPS; ++step) {
        v2f o0p = (v2f){s0, s0};
        v2f o1p = (v2f){s1, s1};
        v2f tq = (v2f){0.f, 0.f};
        v2f D0 = (v2f){0.f, 0.f};
        v2f D1 = (v2f){0.f, 0.f};
        #pragma unroll
        for (int i = 0; i < 5; ++i) {
            v2f e0 = (v2f){E[i].x, E[i].y};
            v2f e1 = (v2f){E[i].z, E[i].w};
            v2f a = fma2(o0p, e0, fma2(o1p, e1, OB[i]));
            a = __builtin_elementwise_max(a, (v2f){0.f, 0.f});
            tq = fma2(a, Wv[i], tq);
            D0 = fma2(a, (v2f){Dv[i].x, Dv[i].y}, D0);
            D1 = fma2(a, (v2f){Dv[i].z, Dv[i].w}, D1);
        }
        float v0 = D0.x + D0.y;
        float v1 = D1.x + D1.y;
        float vt = tq.x + tq.y;
        // cross-ug butterfly (quad_perm DPP)
        v0 += __shfl_xor(v0, 1, 64);  v0 += __shfl_xor(v0, 2, 64);
        v1 += __shfl_xor(v1, 1, 64);  v1 += __shfl_xor(v1, 2, 64);
        vt += __shfl_xor(vt, 1, 64);  vt += __shfl_xor(vt, 2, 64);
        s0 = fmaf(DT, v0, s0);
        s1 = fmaf(DT, v1, s1);
        if (ug == 0) atomicAdd(tp + step * BATCH, vt);
    }
}

// ---------------------------------------------------------------------------
// Phase B: integrate pendulum; prefetch torq; packed float2 state store.
// ---------------------------------------------------------------------------
__global__ __launch_bounds__(256) void pend_kernel(const float* __restrict__ x,
                                                   const float* __restrict__ torq,
                                                   const float* __restrict__ direct,
                                                   const float* __restrict__ fc4_b,
                                                   float* __restrict__ out) {
    int b = blockIdx.x * 256 + threadIdx.x;
    float theta = x[2 * b];
    float omega = 0.f;
    float base = direct[b] + fc4_b[0];
    float2* out_l = (float2*)out;             // (100, 8192, 2)
    float* out_t = out + STEPS * BATCH * 2;   // (100, 8192)
    float pf[4];
    #pragma unroll
    for (int j = 0; j < 4; ++j) pf[j] = torq[j * BATCH + b];
    #pragma unroll 4
    for (int s = 0; s < STEPS; ++s) {
        float tq = base + pf[s & 3];
        if (s + 4 < STEPS) pf[s & 3] = torq[(s + 4) * BATCH + b];
        float alpha = tq - __sinf(theta) - 0.1f * omega;   // old theta, old omega
        theta = fmaf(DT, omega, theta);                    // uses old omega
        omega = fmaf(DT, alpha, omega);
        out_l[s * BATCH + b] = make_float2(theta, omega);
        out_t[s * BATCH + b] = tq;
    }
}

extern "C" void kernel_launch(void* const* d_in, const int* in_sizes, int n_in,
                              void* d_out, int out_size, void* d_ws, size_t ws_size,
                              hipStream_t stream) {
    const float* x     = (const float*)d_in[0];
    const float* fc1_w = (const float*)d_in[1];
    const float* fc1_b = (const float*)d_in[2];
    const float* fc2_w = (const float*)d_in[3];
    const float* fc2_b = (const float*)d_in[4];
    const float* fc3_w = (const float*)d_in[5];
    const float* fc3_b = (const float*)d_in[6];
    const float* fcd_w = (const float*)d_in[7];
    const float* fcd_b = (const float*)d_in[8];
    const float* enc   = (const float*)d_in[9];
    const float* obias = (const float*)d_in[10];
    const float* dec   = (const float*)d_in[11];
    const float* fc4_w = (const float*)d_in[12];
    const float* fc4_b = (const float*)d_in[13];
    float* out = (float*)d_out;
    float* ws = (float*)d_ws;

    float* pc      = ws + WS_PC;
    float* direct  = ws + WS_DIRECT;
    float* o0      = ws + WS_O0;
    float* torq    = ws + WS_TORQ;

    hipLaunchKernelGGL(prep_mlp_kernel, dim3(800 + 256), dim3(256), 0, stream,
                       x, fc1_w, fc1_b, fc2_w, fc2_b, fc3_w, fc3_b,
                       fcd_w, fcd_b, enc, obias, dec, fc4_w,
                       pc, torq, o0, direct);
    hipLaunchKernelGGL(osc_kernel, dim3(25600 / 4), dim3(256), 0, stream,
                       pc, o0, torq);
    hipLaunchKernelGGL(pend_kernel, dim3(BATCH / 256), dim3(256), 0, stream,
                       x, torq, direct, fc4_b, out);
}

// Round 8
// 432.531 us; speedup vs baseline: 1.0954x; 1.0394x over previous
//
#include <hip/hip_runtime.h>

#define N_OSC 50
#define N_PER 40
#define DT 0.01f
#define STEPS 100
#define BATCH 8192

typedef float v2f __attribute__((ext_vector_type(2)));

static __device__ __forceinline__ v2f fma2(v2f a, v2f b, v2f c) {
    return __builtin_elementwise_fma(a, b, c);
}

// ws layout (float offsets)
#define WS_PC     0        // 50*240 = 12000 packed consts
#define WS_DIRECT 12288    // 8192
#define WS_O0     20480    // 100*8192
#define WS_TORQ   839680   // 100*8192 torque accumulator

// ---------------------------------------------------------------------------
// Fused prep + MLP. Blocks [0,800): zero torq; blocks [0,8) pack consts.
// Blocks [800,1312): MLP, 16 batch rows per block (2 blocks/CU machine-wide).
// Packed consts per osc (stride 240 floats):
//   [0..79]    E: chunk c -> (e0 of unit 2c, e0 of 2c+1, e1 of 2c, e1 of 2c+1)
//   [80..159]  D: chunk c -> (d0 of 2c, d0 of 2c+1, d1 of 2c, d1 of 2c+1)
//   [160..199] W: chunk c -> (w4 of 2c, w4 of 2c+1)
//   [200..239] OB: obias[n] natural order
// ---------------------------------------------------------------------------
__global__ __launch_bounds__(256) void prep_mlp_kernel(
    const float* __restrict__ x,
    const float* __restrict__ fc1_w, const float* __restrict__ fc1_b,
    const float* __restrict__ fc2_w, const float* __restrict__ fc2_b,
    const float* __restrict__ fc3_w, const float* __restrict__ fc3_b,
    const float* __restrict__ fcd_w, const float* __restrict__ fcd_b,
    const float* __restrict__ enc, const float* __restrict__ obias,
    const float* __restrict__ dec, const float* __restrict__ fc4_w,
    float* __restrict__ pc, float* __restrict__ torq,
    float* __restrict__ o0out, float* __restrict__ directout) {
    __shared__ float hs[16 * 132];
    __shared__ float h2s[16 * 132];
    int blk = blockIdx.x;
    int tid = threadIdx.x;

    if (blk < 800) {
        int idx = blk * 256 + tid;
        ((float4*)torq)[idx] = make_float4(0.f, 0.f, 0.f, 0.f);  // 819200 floats
        if (idx < N_OSC * N_PER) {
            int o = idx / N_PER, n = idx - o * N_PER;
            int c = n >> 1, h = n & 1;
            float* base = pc + o * 240;
            base[4 * c + h]           = enc[o * 80 + 2 * n + 0];
            base[4 * c + 2 + h]       = enc[o * 80 + 2 * n + 1];
            base[80 + 4 * c + h]      = dec[o * 80 + n];         // dec[o][0][n]
            base[80 + 4 * c + 2 + h]  = dec[o * 80 + 40 + n];    // dec[o][1][n]
            base[160 + 2 * c + h]     = fc4_w[o * 40 + n];
            base[200 + n]             = obias[o * 40 + n];
        }
        return;
    }

    int r = tid & 15;              // batch row in block
    int jg = tid >> 4;             // 0..15 output-group
    int b0 = (blk - 800) * 16;

    // fc1: h = relu(x @ fc1_w.T + b1), 16x128 outputs
    for (int idx = tid; idx < 16 * 128; idx += 256) {
        int rr = idx >> 7, j = idx & 127;
        float x0 = x[(b0 + rr) * 2], x1 = x[(b0 + rr) * 2 + 1];
        float v = fmaf(x0, fc1_w[j * 2], fmaf(x1, fc1_w[j * 2 + 1], fc1_b[j]));
        hs[rr * 132 + j] = fmaxf(v, 0.f);
    }
    __syncthreads();

    // direct = h . fcd_w + fcd_b
    if (tid < 16) {
        float s = fcd_b[0];
        #pragma unroll 8
        for (int k = 0; k < 128; k += 4) {
            float4 h4 = *(const float4*)&hs[tid * 132 + k];
            float4 w4 = *(const float4*)&fcd_w[k];
            s = fmaf(h4.x, w4.x, fmaf(h4.y, w4.y, fmaf(h4.z, w4.z, fmaf(h4.w, w4.w, s))));
        }
        directout[b0 + tid] = s;
    }

    // fc2: h2 = relu(h @ fc2_w.T + b2). 16 jg x 2 passes x 4 j = 128 j.
    for (int pass = 0; pass < 2; ++pass) {
        int j0 = jg * 8 + pass * 4;
        float a0 = fc2_b[j0], a1 = fc2_b[j0 + 1], a2 = fc2_b[j0 + 2], a3 = fc2_b[j0 + 3];
        const float* w0 = fc2_w + j0 * 128;
        const float* w1 = w0 + 128;
        const float* w2 = w0 + 256;
        const float* w3 = w0 + 384;
        #pragma unroll 8
        for (int k = 0; k < 128; k += 4) {
            float4 h4 = *(const float4*)&hs[r * 132 + k];
            float4 q0 = *(const float4*)&w0[k];
            float4 q1 = *(const float4*)&w1[k];
            float4 q2 = *(const float4*)&w2[k];
            float4 q3 = *(const float4*)&w3[k];
            a0 = fmaf(h4.x, q0.x, fmaf(h4.y, q0.y, fmaf(h4.z, q0.z, fmaf(h4.w, q0.w, a0))));
            a1 = fmaf(h4.x, q1.x, fmaf(h4.y, q1.y, fmaf(h4.z, q1.z, fmaf(h4.w, q1.w, a1))));
            a2 = fmaf(h4.x, q2.x, fmaf(h4.y, q2.y, fmaf(h4.z, q2.z, fmaf(h4.w, q2.w, a2))));
            a3 = fmaf(h4.x, q3.x, fmaf(h4.y, q3.y, fmaf(h4.z, q3.z, fmaf(h4.w, q3.w, a3))));
        }
        h2s[r * 132 + j0]     = fmaxf(a0, 0.f);
        h2s[r * 132 + j0 + 1] = fmaxf(a1, 0.f);
        h2s[r * 132 + j0 + 2] = fmaxf(a2, 0.f);
        h2s[r * 132 + j0 + 3] = fmaxf(a3, 0.f);
    }
    __syncthreads();

    // fc3: x3 (100 outputs) -> o0out[j][b]. pass0: j0=jg*4 (0..60);
    // pass1: j0=64+jg*4 for jg<9 (64..96).
    for (int pass = 0; pass < 2; ++pass) {
        int j0 = pass * 64 + jg * 4;
        if (j0 >= 100) continue;
        float a0 = fc3_b[j0], a1 = fc3_b[j0 + 1], a2 = fc3_b[j0 + 2], a3 = fc3_b[j0 + 3];
        const float* w0 = fc3_w + j0 * 128;
        const float* w1 = w0 + 128;
        const float* w2 = w0 + 256;
        const float* w3 = w0 + 384;
        #pragma unroll 8
        for (int k = 0; k < 128; k += 4) {
            float4 h4 = *(const float4*)&h2s[r * 132 + k];
            float4 q0 = *(const float4*)&w0[k];
            float4 q1 = *(const float4*)&w1[k];
            float4 q2 = *(const float4*)&w2[k];
            float4 q3 = *(const float4*)&w3[k];
            a0 = fmaf(h4.x, q0.x, fmaf(h4.y, q0.y, fmaf(h4.z, q0.z, fmaf(h4.w, q0.w, a0))));
            a1 = fmaf(h4.x, q1.x, fmaf(h4.y, q1.y, fmaf(h4.z, q1.z, fmaf(h4.w, q1.w, a1))));
            a2 = fmaf(h4.x, q2.x, fmaf(h4.y, q2.y, fmaf(h4.z, q2.z, fmaf(h4.w, q2.w, a2))));
            a3 = fmaf(h4.x, q3.x, fmaf(h4.y, q3.y, fmaf(h4.z, q3.z, fmaf(h4.w, q3.w, a3))));
        }
        o0out[(j0)     * BATCH + b0 + r] = a0;
        o0out[(j0 + 1) * BATCH + b0 + r] = a1;
        o0out[(j0 + 2) * BATCH + b0 + r] = a2;
        o0out[(j0 + 3) * BATCH + b0 + r] = a3;
    }
}

// ---------------------------------------------------------------------------
// Phase A: ONE OSC PER WAVE, 64 batch lanes, all 40 units register-resident.
// amdgpu_waves_per_eu(1,1): tells the scheduler its occupancy target is 1
// wave/EU, so it stops minimizing register pressure and keeps the ~200-VGPR
// constant set live (the R3-R7 failure mode was the occupancy-first
// heuristic reloading constants every step). Constants loaded through an
// opaque (asm-perturbed) address so uniformity analysis can't scalarize
// them to SGPR reloads; then asm-pinned. obias -> SGPRs via readfirstlane,
// used only as pk_fma addend (<=1 scalar operand per op). Hot loop: 120
// v_pk_fma/pk_max + tail, zero memory ops except the fire-and-forget atomic.
// ---------------------------------------------------------------------------
__global__ __attribute__((amdgpu_waves_per_eu(1, 1))) __launch_bounds__(64)
void osc_kernel(const float* __restrict__ pc,
                const float* __restrict__ o0init,
                float* __restrict__ torq) {
    int blk = blockIdx.x;
    int bg = blk / N_OSC;          // 0..127
    int osc = blk - bg * N_OSC;    // 0..49
    int lane = threadIdx.x;
    int b = bg * 64 + lane;

    // Opaque zero defeats uniformity analysis -> loads stay vector loads.
    int zero = 0;
    asm volatile("" : "+v"(zero));
    const float* __restrict__ base = pc + osc * 240 + zero;

    v2f e0[20], e1[20], d0c[20], d1c[20], wcv[20];
    #pragma unroll
    for (int c = 0; c < 20; ++c) {
        float4 q = *(const float4*)(base + 4 * c);
        e0[c] = (v2f){q.x, q.y};
        e1[c] = (v2f){q.z, q.w};
        float4 d = *(const float4*)(base + 80 + 4 * c);
        d0c[c] = (v2f){d.x, d.y};
        d1c[c] = (v2f){d.z, d.w};
        wcv[c] = *(const v2f*)(base + 160 + 2 * c);
    }
    #pragma unroll
    for (int c = 0; c < 20; ++c) {
        asm volatile("" : "+v"(e0[c]));
        asm volatile("" : "+v"(e1[c]));
        asm volatile("" : "+v"(d0c[c]));
        asm volatile("" : "+v"(d1c[c]));
        asm volatile("" : "+v"(wcv[c]));
    }

    // obias -> SGPRs (wave-uniform values; readfirstlane is exact here).
    float ob[40];
    #pragma unroll
    for (int n = 0; n < 40; ++n) {
        union { float f; int i; } u;
        u.f = base[200 + n];
        u.i = __builtin_amdgcn_readfirstlane(u.i);
        ob[n] = u.f;
    }

    float s0 = o0init[(2 * osc) * BATCH + b];
    float s1 = o0init[(2 * osc + 1) * BATCH + b];
    float* tp = torq + b;

    for (int step = 0; step < STEPS; ++step) {
        v2f o0p = (v2f){s0, s0};
        v2f o1p = (v2f){s1, s1};
        v2f tq = (v2f){0.f, 0.f};
        v2f D0 = (v2f){0.f, 0.f};
        v2f D1 = (v2f){0.f, 0.f};
        #pragma unroll
        for (int i = 0; i < 20; ++i) {
            v2f obp = (v2f){ob[2 * i], ob[2 * i + 1]};
            v2f a = fma2(o0p, e0[i], fma2(o1p, e1[i], obp));
            a = __builtin_elementwise_max(a, (v2f){0.f, 0.f});
            tq = fma2(a, wcv[i], tq);
            D0 = fma2(a, d0c[i], D0);
            D1 = fma2(a, d1c[i], D1);
        }
        s0 = fmaf(DT, D0.x + D0.y, s0);
        s1 = fmaf(DT, D1.x + D1.y, s1);
        atomicAdd(tp + step * BATCH, tq.x + tq.y);
    }
}

// ---------------------------------------------------------------------------
// Phase B: integrate pendulum; prefetch torq; packed float2 state store.
// ---------------------------------------------------------------------------
__global__ __launch_bounds__(64) void pend_kernel(const float* __restrict__ x,
                                                  const float* __restrict__ torq,
                                                  const float* __restrict__ direct,
                                                  const float* __restrict__ fc4_b,
                                                  float* __restrict__ out) {
    int b = blockIdx.x * 64 + threadIdx.x;
    float theta = x[2 * b];
    float omega = 0.f;
    float base = direct[b] + fc4_b[0];
    float2* out_l = (float2*)out;             // (100, 8192, 2)
    float* out_t = out + STEPS * BATCH * 2;   // (100, 8192)
    float pf[4];
    #pragma unroll
    for (int j = 0; j < 4; ++j) pf[j] = torq[j * BATCH + b];
    #pragma unroll 4
    for (int s = 0; s < STEPS; ++s) {
        float tq = base + pf[s & 3];
        if (s + 4 < STEPS) pf[s & 3] = torq[(s + 4) * BATCH + b];
        float alpha = tq - __sinf(theta) - 0.1f * omega;   // old theta, old omega
        theta = fmaf(DT, omega, theta);                    // uses old omega
        omega = fmaf(DT, alpha, omega);
        out_l[s * BATCH + b] = make_float2(theta, omega);
        out_t[s * BATCH + b] = tq;
    }
}

extern "C" void kernel_launch(void* const* d_in, const int* in_sizes, int n_in,
                              void* d_out, int out_size, void* d_ws, size_t ws_size,
                              hipStream_t stream) {
    const float* x     = (const float*)d_in[0];
    const float* fc1_w = (const float*)d_in[1];
    const float* fc1_b = (const float*)d_in[2];
    const float* fc2_w = (const float*)d_in[3];
    const float* fc2_b = (const float*)d_in[4];
    const float* fc3_w = (const float*)d_in[5];
    const float* fc3_b = (const float*)d_in[6];
    const float* fcd_w = (const float*)d_in[7];
    const float* fcd_b = (const float*)d_in[8];
    const float* enc   = (const float*)d_in[9];
    const float* obias = (const float*)d_in[10];
    const float* dec   = (const float*)d_in[11];
    const float* fc4_w = (const float*)d_in[12];
    const float* fc4_b = (const float*)d_in[13];
    float* out = (float*)d_out;
    float* ws = (float*)d_ws;

    float* pc      = ws + WS_PC;
    float* direct  = ws + WS_DIRECT;
    float* o0      = ws + WS_O0;
    float* torq    = ws + WS_TORQ;

    hipLaunchKernelGGL(prep_mlp_kernel, dim3(800 + 512), dim3(256), 0, stream,
                       x, fc1_w, fc1_b, fc2_w, fc2_b, fc3_w, fc3_b,
                       fcd_w, fcd_b, enc, obias, dec, fc4_w,
                       pc, torq, o0, direct);
    hipLaunchKernelGGL(osc_kernel, dim3(128 * N_OSC), dim3(64), 0, stream,
                       pc, o0, torq);
    hipLaunchKernelGGL(pend_kernel, dim3(BATCH / 64), dim3(64), 0, stream,
                       x, torq, direct, fc4_b, out);
}

// Round 9
// 428.534 us; speedup vs baseline: 1.1056x; 1.0093x over previous
//
#include <hip/hip_runtime.h>

#define N_OSC 50
#define N_PER 40
#define DT 0.01f
#define STEPS 100
#define BATCH 8192

typedef float v2f __attribute__((ext_vector_type(2)));

static __device__ __forceinline__ v2f fma2(v2f a, v2f b, v2f c) {
    return __builtin_elementwise_fma(a, b, c);
}

// ws layout (float offsets)
#define WS_PC     0        // 50*240 = 12000 packed consts
#define WS_DIRECT 12288    // 8192
#define WS_O0     20480    // 100*8192
#define WS_TORQ   839680   // 100*8192 torque accumulator

// ---------------------------------------------------------------------------
// Fused prep + MLP. Blocks [0,800): zero torq; blocks [0,8) pack consts.
// Blocks [800,1312): MLP, 16 batch rows per block.
// Packed consts per osc (stride 240 floats):
//   [0..79]    E: chunk c -> (e0 of unit 2c, e0 of 2c+1, e1 of 2c, e1 of 2c+1)
//   [80..159]  D: chunk c -> (d0 of 2c, d0 of 2c+1, d1 of 2c, d1 of 2c+1)
//   [160..199] W: chunk c -> (w4 of 2c, w4 of 2c+1)
//   [200..239] OB: chunk c -> (ob of 2c, ob of 2c+1)
// ---------------------------------------------------------------------------
__global__ __launch_bounds__(256) void prep_mlp_kernel(
    const float* __restrict__ x,
    const float* __restrict__ fc1_w, const float* __restrict__ fc1_b,
    const float* __restrict__ fc2_w, const float* __restrict__ fc2_b,
    const float* __restrict__ fc3_w, const float* __restrict__ fc3_b,
    const float* __restrict__ fcd_w, const float* __restrict__ fcd_b,
    const float* __restrict__ enc, const float* __restrict__ obias,
    const float* __restrict__ dec, const float* __restrict__ fc4_w,
    float* __restrict__ pc, float* __restrict__ torq,
    float* __restrict__ o0out, float* __restrict__ directout) {
    __shared__ float hs[16 * 132];
    __shared__ float h2s[16 * 132];
    int blk = blockIdx.x;
    int tid = threadIdx.x;

    if (blk < 800) {
        int idx = blk * 256 + tid;
        ((float4*)torq)[idx] = make_float4(0.f, 0.f, 0.f, 0.f);  // 819200 floats
        if (idx < N_OSC * N_PER) {
            int o = idx / N_PER, n = idx - o * N_PER;
            int c = n >> 1, h = n & 1;
            float* base = pc + o * 240;
            base[4 * c + h]           = enc[o * 80 + 2 * n + 0];
            base[4 * c + 2 + h]       = enc[o * 80 + 2 * n + 1];
            base[80 + 4 * c + h]      = dec[o * 80 + n];         // dec[o][0][n]
            base[80 + 4 * c + 2 + h]  = dec[o * 80 + 40 + n];    // dec[o][1][n]
            base[160 + 2 * c + h]     = fc4_w[o * 40 + n];
            base[200 + 2 * c + h]     = obias[o * 40 + n];
        }
        return;
    }

    int r = tid & 15;              // batch row in block
    int jg = tid >> 4;             // 0..15 output-group
    int b0 = (blk - 800) * 16;

    // fc1: h = relu(x @ fc1_w.T + b1), 16x128 outputs
    for (int idx = tid; idx < 16 * 128; idx += 256) {
        int rr = idx >> 7, j = idx & 127;
        float x0 = x[(b0 + rr) * 2], x1 = x[(b0 + rr) * 2 + 1];
        float v = fmaf(x0, fc1_w[j * 2], fmaf(x1, fc1_w[j * 2 + 1], fc1_b[j]));
        hs[rr * 132 + j] = fmaxf(v, 0.f);
    }
    __syncthreads();

    // direct = h . fcd_w + fcd_b
    if (tid < 16) {
        float s = fcd_b[0];
        #pragma unroll 8
        for (int k = 0; k < 128; k += 4) {
            float4 h4 = *(const float4*)&hs[tid * 132 + k];
            float4 w4 = *(const float4*)&fcd_w[k];
            s = fmaf(h4.x, w4.x, fmaf(h4.y, w4.y, fmaf(h4.z, w4.z, fmaf(h4.w, w4.w, s))));
        }
        directout[b0 + tid] = s;
    }

    // fc2: h2 = relu(h @ fc2_w.T + b2). 16 jg x 2 passes x 4 j = 128 j.
    for (int pass = 0; pass < 2; ++pass) {
        int j0 = jg * 8 + pass * 4;
        float a0 = fc2_b[j0], a1 = fc2_b[j0 + 1], a2 = fc2_b[j0 + 2], a3 = fc2_b[j0 + 3];
        const float* w0 = fc2_w + j0 * 128;
        const float* w1 = w0 + 128;
        const float* w2 = w0 + 256;
        const float* w3 = w0 + 384;
        #pragma unroll 8
        for (int k = 0; k < 128; k += 4) {
            float4 h4 = *(const float4*)&hs[r * 132 + k];
            float4 q0 = *(const float4*)&w0[k];
            float4 q1 = *(const float4*)&w1[k];
            float4 q2 = *(const float4*)&w2[k];
            float4 q3 = *(const float4*)&w3[k];
            a0 = fmaf(h4.x, q0.x, fmaf(h4.y, q0.y, fmaf(h4.z, q0.z, fmaf(h4.w, q0.w, a0))));
            a1 = fmaf(h4.x, q1.x, fmaf(h4.y, q1.y, fmaf(h4.z, q1.z, fmaf(h4.w, q1.w, a1))));
            a2 = fmaf(h4.x, q2.x, fmaf(h4.y, q2.y, fmaf(h4.z, q2.z, fmaf(h4.w, q2.w, a2))));
            a3 = fmaf(h4.x, q3.x, fmaf(h4.y, q3.y, fmaf(h4.z, q3.z, fmaf(h4.w, q3.w, a3))));
        }
        h2s[r * 132 + j0]     = fmaxf(a0, 0.f);
        h2s[r * 132 + j0 + 1] = fmaxf(a1, 0.f);
        h2s[r * 132 + j0 + 2] = fmaxf(a2, 0.f);
        h2s[r * 132 + j0 + 3] = fmaxf(a3, 0.f);
    }
    __syncthreads();

    // fc3: x3 (100 outputs) -> o0out[j][b]
    for (int pass = 0; pass < 2; ++pass) {
        int j0 = pass * 64 + jg * 4;
        if (j0 >= 100) continue;
        float a0 = fc3_b[j0], a1 = fc3_b[j0 + 1], a2 = fc3_b[j0 + 2], a3 = fc3_b[j0 + 3];
        const float* w0 = fc3_w + j0 * 128;
        const float* w1 = w0 + 128;
        const float* w2 = w0 + 256;
        const float* w3 = w0 + 384;
        #pragma unroll 8
        for (int k = 0; k < 128; k += 4) {
            float4 h4 = *(const float4*)&h2s[r * 132 + k];
            float4 q0 = *(const float4*)&w0[k];
            float4 q1 = *(const float4*)&w1[k];
            float4 q2 = *(const float4*)&w2[k];
            float4 q3 = *(const float4*)&w3[k];
            a0 = fmaf(h4.x, q0.x, fmaf(h4.y, q0.y, fmaf(h4.z, q0.z, fmaf(h4.w, q0.w, a0))));
            a1 = fmaf(h4.x, q1.x, fmaf(h4.y, q1.y, fmaf(h4.z, q1.z, fmaf(h4.w, q1.w, a1))));
            a2 = fmaf(h4.x, q2.x, fmaf(h4.y, q2.y, fmaf(h4.z, q2.z, fmaf(h4.w, q2.w, a2))));
            a3 = fmaf(h4.x, q3.x, fmaf(h4.y, q3.y, fmaf(h4.z, q3.z, fmaf(h4.w, q3.w, a3))));
        }
        o0out[(j0)     * BATCH + b0 + r] = a0;
        o0out[(j0 + 1) * BATCH + b0 + r] = a1;
        o0out[(j0 + 2) * BATCH + b0 + r] = a2;
        o0out[(j0 + 3) * BATCH + b0 + r] = a3;
    }
}

// ---------------------------------------------------------------------------
// Phase A: one oscillator per WAVE, units split across lane quads (R7
// structure — verified correct). ug = lane&3 owns 10 units (5 chunks, 60
// const floats/lane); bl = lane>>2 -> 16 batch elems/wave. Cross-ug
// reduction = __shfl_xor(1,2) quad butterfly (pure VALU). The R7 failure
// was the allocator's DEFAULT 8-waves/EU pressure target (~64 VGPR):
// needing ~85, it reloaded constants from L2 every step (FETCH 2x, VALU
// bloat). amdgpu_waves_per_eu(4,4) raises the budget to 128 VGPRs >> 85 so
// constants stay genuinely register-resident, with 4 waves/SIMD to hide
// remaining latency.
// ---------------------------------------------------------------------------
__global__ __attribute__((amdgpu_waves_per_eu(4, 4))) __launch_bounds__(256)
void osc_kernel(const float* __restrict__ pc,
                const float* __restrict__ o0init,
                float* __restrict__ torq) {
    int tid = threadIdx.x;
    int w = __builtin_amdgcn_readfirstlane(tid >> 6);
    int lane = tid & 63;
    int W = blockIdx.x * 4 + w;        // 0..25599
    int bg = W / N_OSC;                // 0..511
    int osc = W - bg * N_OSC;          // 0..49
    int ug = lane & 3;
    int b = bg * 16 + (lane >> 2);

    const float* __restrict__ base = pc + osc * 240;

    float4 E[5], Dv[5];
    v2f Wv[5], OB[5];
    #pragma unroll
    for (int i = 0; i < 5; ++i) {
        int c = ug * 5 + i;
        E[i]  = *(const float4*)(base + 4 * c);        // e0(2c),e0(2c+1),e1(2c),e1(2c+1)
        Dv[i] = *(const float4*)(base + 80 + 4 * c);   // d0 pair, d1 pair
        Wv[i] = *(const v2f*)(base + 160 + 2 * c);
        OB[i] = *(const v2f*)(base + 200 + 2 * c);
    }
    #pragma unroll
    for (int i = 0; i < 5; ++i) {
        asm volatile("" : "+v"(E[i].x), "+v"(E[i].y), "+v"(E[i].z), "+v"(E[i].w));
        asm volatile("" : "+v"(Dv[i].x), "+v"(Dv[i].y), "+v"(Dv[i].z), "+v"(Dv[i].w));
        asm volatile("" : "+v"(Wv[i]), "+v"(OB[i]));
    }

    float s0 = o0init[(2 * osc) * BATCH + b];
    float s1 = o0init[(2 * osc + 1) * BATCH + b];
    float* tp = torq + b;

    for (int step = 0; step < STEPS; ++step) {
        v2f o0p = (v2f){s0, s0};
        v2f o1p = (v2f){s1, s1};
        v2f tq = (v2f){0.f, 0.f};
        v2f D0 = (v2f){0.f, 0.f};
        v2f D1 = (v2f){0.f, 0.f};
        #pragma unroll
        for (int i = 0; i < 5; ++i) {
            v2f e0 = (v2f){E[i].x, E[i].y};
            v2f e1 = (v2f){E[i].z, E[i].w};
            v2f a = fma2(o0p, e0, fma2(o1p, e1, OB[i]));
            a = __builtin_elementwise_max(a, (v2f){0.f, 0.f});
            tq = fma2(a, Wv[i], tq);
            D0 = fma2(a, (v2f){Dv[i].x, Dv[i].y}, D0);
            D1 = fma2(a, (v2f){Dv[i].z, Dv[i].w}, D1);
        }
        float v0 = D0.x + D0.y;
        float v1 = D1.x + D1.y;
        float vt = tq.x + tq.y;
        // cross-ug butterfly (quad_perm DPP)
        v0 += __shfl_xor(v0, 1, 64);  v0 += __shfl_xor(v0, 2, 64);
        v1 += __shfl_xor(v1, 1, 64);  v1 += __shfl_xor(v1, 2, 64);
        vt += __shfl_xor(vt, 1, 64);  vt += __shfl_xor(vt, 2, 64);
        s0 = fmaf(DT, v0, s0);
        s1 = fmaf(DT, v1, s1);
        if (ug == 0) atomicAdd(tp + step * BATCH, vt);
    }
}

// ---------------------------------------------------------------------------
// Phase B: integrate pendulum; prefetch torq; packed float2 state store.
// ---------------------------------------------------------------------------
__global__ __launch_bounds__(256) void pend_kernel(const float* __restrict__ x,
                                                   const float* __restrict__ torq,
                                                   const float* __restrict__ direct,
                                                   const float* __restrict__ fc4_b,
                                                   float* __restrict__ out) {
    int b = blockIdx.x * 256 + threadIdx.x;
    float theta = x[2 * b];
    float omega = 0.f;
    float base = direct[b] + fc4_b[0];
    float2* out_l = (float2*)out;             // (100, 8192, 2)
    float* out_t = out + STEPS * BATCH * 2;   // (100, 8192)
    float pf[4];
    #pragma unroll
    for (int j = 0; j < 4; ++j) pf[j] = torq[j * BATCH + b];
    #pragma unroll 4
    for (int s = 0; s < STEPS; ++s) {
        float tq = base + pf[s & 3];
        if (s + 4 < STEPS) pf[s & 3] = torq[(s + 4) * BATCH + b];
        float alpha = tq - __sinf(theta) - 0.1f * omega;   // old theta, old omega
        theta = fmaf(DT, omega, theta);                    // uses old omega
        omega = fmaf(DT, alpha, omega);
        out_l[s * BATCH + b] = make_float2(theta, omega);
        out_t[s * BATCH + b] = tq;
    }
}

extern "C" void kernel_launch(void* const* d_in, const int* in_sizes, int n_in,
                              void* d_out, int out_size, void* d_ws, size_t ws_size,
                              hipStream_t stream) {
    const float* x     = (const float*)d_in[0];
    const float* fc1_w = (const float*)d_in[1];
    const float* fc1_b = (const float*)d_in[2];
    const float* fc2_w = (const float*)d_in[3];
    const float* fc2_b = (const float*)d_in[4];
    const float* fc3_w = (const float*)d_in[5];
    const float* fc3_b = (const float*)d_in[6];
    const float* fcd_w = (const float*)d_in[7];
    const float* fcd_b = (const float*)d_in[8];
    const float* enc   = (const float*)d_in[9];
    const float* obias = (const float*)d_in[10];
    const float* dec   = (const float*)d_in[11];
    const float* fc4_w = (const float*)d_in[12];
    const float* fc4_b = (const float*)d_in[13];
    float* out = (float*)d_out;
    float* ws = (float*)d_ws;

    float* pc      = ws + WS_PC;
    float* direct  = ws + WS_DIRECT;
    float* o0      = ws + WS_O0;
    float* torq    = ws + WS_TORQ;

    hipLaunchKernelGGL(prep_mlp_kernel, dim3(800 + 512), dim3(256), 0, stream,
                       x, fc1_w, fc1_b, fc2_w, fc2_b, fc3_w, fc3_b,
                       fcd_w, fcd_b, enc, obias, dec, fc4_w,
                       pc, torq, o0, direct);
    hipLaunchKernelGGL(osc_kernel, dim3(25600 / 4), dim3(256), 0, stream,
                       pc, o0, torq);
    hipLaunchKernelGGL(pend_kernel, dim3(BATCH / 256), dim3(256), 0, stream,
                       x, torq, direct, fc4_b, out);
}